// Round 1
// baseline (11.969 us; speedup 1.0000x reference)
//
#include <hip/hip_runtime.h>
#include <math.h>

// Problem constants from the reference
#define M_ 16
#define J_ 2
#define I_ 3
#define L_ 2
#define W_ 9
#define STEEP_ 10.0f

// One block, one wave (64 threads). Lane i (i<16) owns m=i; lanes 16..63
// redundantly compute m = lane&15 (keeps shuffle groups uniform, no divergence).
__global__ void algelogic_kernel(const float* __restrict__ state,      // (W*L)=18
                                 const float* __restrict__ constants,  // (M,J+1,L)=16*3*2
                                 const float* __restrict__ gammas,     // (M,J+1,L)
                                 const float* __restrict__ head_w,     // (M,J,I,L)=16*2*3*2
                                 const float* __restrict__ tail_w,     // (M,L,I)=16*2*3
                                 const float* __restrict__ tail_b,     // (M,L)=16*2
                                 float* __restrict__ out)              // (M)
{
    const int lane = threadIdx.x;
    const int m = lane & (M_ - 1);

    float cap_vars[I_] = {0.0f, 0.0f, 0.0f};

    #pragma unroll
    for (int j = 0; j < J_; ++j) {
        // g = gammas[m, j+1, :], c = constants[m, j, :]
        const float g0 = gammas[m * ((J_ + 1) * L_) + (j + 1) * L_ + 0];
        const float g1 = gammas[m * ((J_ + 1) * L_) + (j + 1) * L_ + 1];
        const float c0 = constants[m * ((J_ + 1) * L_) + j * L_ + 0];
        const float c1 = constants[m * ((J_ + 1) * L_) + j * L_ + 1];

        // sigmoid(STEEP*(g-0.5))
        const float s0 = 1.0f / (1.0f + expf(-STEEP_ * (g0 - 0.5f)));
        const float s1 = 1.0f / (1.0f + expf(-STEEP_ * (g1 - 0.5f)));

        // argmin over w of sig·(c - wm[w])², first-occurrence tie-break
        int best = 0;
        float bestq = 3.402823466e+38f;
        #pragma unroll
        for (int w = 0; w < W_; ++w) {
            const float d0 = c0 - state[w * L_ + 0];
            const float d1 = c1 - state[w * L_ + 1];
            const float q = s0 * d0 * d0 + s1 * d1 * d1;
            if (q < bestq) { bestq = q; best = w; }
        }

        const float vm0 = (g0 > 0.5f) ? 1.0f : 0.0f;
        const float vm1 = (g1 > 0.5f) ? 1.0f : 0.0f;
        const float w0 = state[best * L_ + 0];
        const float w1 = state[best * L_ + 1];

        #pragma unroll
        for (int i = 0; i < I_; ++i) {
            const float hw0 = head_w[m * (J_ * I_ * L_) + j * (I_ * L_) + i * L_ + 0];
            const float hw1 = head_w[m * (J_ * I_ * L_) + j * (I_ * L_) + i * L_ + 1];
            cap_vars[i] += vm0 * hw0 * w0 + vm1 * hw1 * w1;
        }
    }

    // conclusion[l] = sum_i tail_w[m,l,i]*cap_vars[i] + tail_b[m,l]
    float con0 = tail_b[m * L_ + 0];
    float con1 = tail_b[m * L_ + 1];
    #pragma unroll
    for (int i = 0; i < I_; ++i) {
        con0 += tail_w[m * (L_ * I_) + 0 * I_ + i] * cap_vars[i];
        con1 += tail_w[m * (L_ * I_) + 1 * I_ + i] * cap_vars[i];
    }
    const float P = sqrtf(con0 * con0 + con1 * con1);

    // softmax over the 16 m's, within each 16-lane subgroup
    float mx = P;
    #pragma unroll
    for (int d = 1; d < M_; d <<= 1) {
        mx = fmaxf(mx, __shfl_xor(mx, d, M_));
    }
    const float e = expf(P - mx);
    float sum = e;
    #pragma unroll
    for (int d = 1; d < M_; d <<= 1) {
        sum += __shfl_xor(sum, d, M_);
    }

    if (lane < M_) out[m] = e / sum;
}

extern "C" void kernel_launch(void* const* d_in, const int* in_sizes, int n_in,
                              void* d_out, int out_size, void* d_ws, size_t ws_size,
                              hipStream_t stream) {
    const float* state     = (const float*)d_in[0];
    const float* constants = (const float*)d_in[1];
    const float* gammas    = (const float*)d_in[2];
    const float* head_w    = (const float*)d_in[3];
    const float* tail_w    = (const float*)d_in[4];
    const float* tail_b    = (const float*)d_in[5];
    float* out = (float*)d_out;

    algelogic_kernel<<<dim3(1), dim3(64), 0, stream>>>(
        state, constants, gammas, head_w, tail_w, tail_b, out);
}